// Round 1
// 5541.294 us; speedup vs baseline: 1.0732x; 1.0732x over previous
//
#include <hip/hip_runtime.h>

// ---------------------------------------------------------------------------
// Direct 3x3 SAME conv + ReLU, fp32, row-range aware, v2.
//
// Block: 256 threads = 32-wide x 16-tall output tile. Thread (lx, yg) owns
// P=2 output rows (yg*P + p) of one 32-col slice. CB output channels per
// block accumulate in VGPRs (acc[CB][P]).
//
// Per input channel ci:
//   - prefetch ci+1's 18x34 halo tile into 3 regs/thread (global loads
//     issued before the FMA block -> latency hidden under 576 FMAs)
//   - 12 LDS reads (4 rows x 3 cols) feed CB*P*9 = 576 FMAs with
//     wave-uniform weight loads (s_load -> v_fmac with SGPR operand)
//   - ds_write prefetched tile into the other LDS buffer
//   - ONE __syncthreads per ci (double-buffered; was 2)
//
// LDS bank geometry: reads tile[yb+r][lx+c] -> each half-wave spans 32
// consecutive columns = all 32 banks; 2 y-groups per wave = 2-way (free).
// Staging writes are linear in t (conflict-free).
//
// Input buffer holds rows [in_y0, in_y0+in_rows); output receives rows
// [out_y0, out_y0+out_rows). Sampling outside the buffer rows / [0,W) cols
// yields zero == SAME padding (strip buffers always contain every in-image
// row a consumer needs).
// ---------------------------------------------------------------------------
template<int CIN, int COUT, int CB, int P>
__global__ __launch_bounds__(256) void conv3x3_relu_k(
    const float* __restrict__ in, const float* __restrict__ wt,
    float* __restrict__ out,
    int W, int in_y0, int in_rows, int out_y0, int out_rows)
{
  constexpr int NCB = (COUT + CB - 1) / CB;
  constexpr int TH  = 8 * P;           // tile height (16 for P=2)
  constexpr int TW  = 32;              // tile width
  constexpr int SW  = TW + 2;          // LDS row stride (34)
  constexpr int NST = (TH + 2) * SW;   // staged elements (612 for P=2)
  constexpr int NLD = (NST + 255) / 256;

  const int n   = blockIdx.z / NCB;    // image index
  const int co0 = (blockIdx.z % NCB) * CB;
  const int lx  = threadIdx.x & 31;
  const int yg  = threadIdx.x >> 5;
  const int x0  = blockIdx.x * TW;
  const int oy0 = out_y0 + blockIdx.y * TH;   // image row of tile top
  const int x   = x0 + lx;
  const int yb  = yg * P;              // tile-row of this thread's first output

  __shared__ float tile[2][TH + 2][SW];

  float acc[CB][P];
#pragma unroll
  for (int j = 0; j < CB; ++j)
#pragma unroll
    for (int p = 0; p < P; ++p) acc[j][p] = 0.f;

  const float* inN = in + (size_t)n * CIN * in_rows * W;

  // ---- stage ci=0 into buffer 0 ----
  {
    const float* ip = inN;
    float* dst = &tile[0][0][0];
#pragma unroll
    for (int u = 0; u < NLD; ++u) {
      int t = threadIdx.x + u * 256;
      if (t < NST) {
        int r = t / SW, c = t - r * SW;
        int yi = oy0 + r - 1 - in_y0;        // buffer-relative row
        int xi = x0 + c - 1;
        float v = 0.f;
        if (yi >= 0 && yi < in_rows && xi >= 0 && xi < W)
          v = ip[(size_t)yi * W + xi];
        dst[t] = v;
      }
    }
  }
  __syncthreads();

  int cur = 0;
#pragma unroll 1
  for (int ci = 0; ci < CIN; ++ci) {
    // ---- prefetch next channel's tile into registers ----
    float pf[NLD];
    if (ci + 1 < CIN) {
      const float* ip = inN + (size_t)(ci + 1) * in_rows * W;
#pragma unroll
      for (int u = 0; u < NLD; ++u) {
        int t = threadIdx.x + u * 256;
        pf[u] = 0.f;
        if (t < NST) {
          int r = t / SW, c = t - r * SW;
          int yi = oy0 + r - 1 - in_y0;
          int xi = x0 + c - 1;
          if (yi >= 0 && yi < in_rows && xi >= 0 && xi < W)
            pf[u] = ip[(size_t)yi * W + xi];
        }
      }
    }

    // ---- compute from tile[cur] ----
    float v[P + 2][3];
#pragma unroll
    for (int r = 0; r < P + 2; ++r) {
      v[r][0] = tile[cur][yb + r][lx + 0];
      v[r][1] = tile[cur][yb + r][lx + 1];
      v[r][2] = tile[cur][yb + r][lx + 2];
    }

#pragma unroll
    for (int j = 0; j < CB; ++j) {
      int co = co0 + j;
      if (COUT % CB != 0) { if (co >= COUT) co = COUT - 1; }  // clamp (dead when exact)
      const float* wp = wt + ((size_t)co * CIN + ci) * 9;     // wave-uniform -> s_load
      const float w0 = wp[0], w1 = wp[1], w2 = wp[2];
      const float w3 = wp[3], w4 = wp[4], w5 = wp[5];
      const float w6 = wp[6], w7 = wp[7], w8 = wp[8];
#pragma unroll
      for (int p = 0; p < P; ++p) {
        float a = acc[j][p];
        a = fmaf(v[p + 0][0], w0, a); a = fmaf(v[p + 0][1], w1, a); a = fmaf(v[p + 0][2], w2, a);
        a = fmaf(v[p + 1][0], w3, a); a = fmaf(v[p + 1][1], w4, a); a = fmaf(v[p + 1][2], w5, a);
        a = fmaf(v[p + 2][0], w6, a); a = fmaf(v[p + 2][1], w7, a); a = fmaf(v[p + 2][2], w8, a);
        acc[j][p] = a;
      }
    }

    // ---- write prefetched tile into the other buffer ----
    if (ci + 1 < CIN) {
      float* dst = &tile[cur ^ 1][0][0];
#pragma unroll
      for (int u = 0; u < NLD; ++u) {
        int t = threadIdx.x + u * 256;
        if (t < NST) dst[t] = pf[u];
      }
    }
    __syncthreads();
    cur ^= 1;
  }

  // ---- epilogue: ReLU + store ----
  float* outN = out + (size_t)n * COUT * out_rows * W;
#pragma unroll
  for (int p = 0; p < P; ++p) {
    const int orow = (oy0 + yb + p) - out_y0;
    if (orow < out_rows) {
#pragma unroll
      for (int j = 0; j < CB; ++j) {
        const int co = co0 + j;
        if (co < COUT) {
          float val = acc[j][p] < 0.f ? 0.f : acc[j][p];
          outN[((size_t)co * out_rows + orow) * W + x] = val;
        }
      }
    }
  }
}

// ---------------------------------------------------------------------------
// PixelShuffle r=4 + ReLU, BOTH images: (2,16,256,256) -> (2,1024,1024)
// out[n, 4*hh+ii, 4*ww+jj] = in[n, ii*4+jj, hh, ww]
// ---------------------------------------------------------------------------
__global__ __launch_bounds__(256) void pixel_shuffle_relu_k(
    const float* __restrict__ in, float* __restrict__ out)
{
  int i = blockIdx.x * 256 + threadIdx.x;      // over 2*1024*1024
  int n = i >> 20;
  int p = i & 1048575;
  int x = p & 1023, y = p >> 10;
  int c = (y & 3) * 4 + (x & 3);
  float v = in[((size_t)(n * 16 + c) * 256 + (y >> 2)) * 256 + (x >> 2)];
  out[i] = v < 0.f ? 0.f : v;
}

// ---------------------------------------------------------------------------
// Per-pixel 5x5 dynamic conv + residual, one image, one row-strip:
// out[y,x] = h[y,x] + sum_{kw,kh} h_pad[y+kh-2, x+kw-2] * ker[kw*5+kh, y, x]
// ker holds rows [ky0, ky0+krows) of the image (channel stride krows*1024).
// ---------------------------------------------------------------------------
__global__ __launch_bounds__(256) void pixel_conv_add_k(
    const float* __restrict__ h,    // full image (1024,1024)
    const float* __restrict__ ker,  // (25, krows, 1024)
    float* __restrict__ out,        // full image (1024,1024)
    int ky0, int krows)
{
  const int tx = threadIdx.x & 15, ty = threadIdx.x >> 4;
  const int x0 = blockIdx.x * 16;
  const int y0 = ky0 + blockIdx.y * 16;

  __shared__ float tile[20][21];
  for (int t = threadIdx.x; t < 20 * 20; t += 256) {
    int r = t / 20, c = t - r * 20;
    int yy = y0 + r - 2, xx = x0 + c - 2;
    float v = 0.f;
    if (yy >= 0 && yy < 1024 && xx >= 0 && xx < 1024) v = h[(size_t)yy * 1024 + xx];
    tile[r][c] = v;
  }
  __syncthreads();

  const int x = x0 + tx, y = y0 + ty;
  float acc = tile[ty + 2][tx + 2];            // residual h
  const size_t kpix = (size_t)(y - ky0) * 1024 + x;
#pragma unroll
  for (int kw = 0; kw < 5; ++kw) {
#pragma unroll
    for (int kh = 0; kh < 5; ++kh) {
      float kv = ker[(size_t)(kw * 5 + kh) * krows * 1024 + kpix];
      acc = fmaf(tile[ty + kh][tx + kw], kv, acc);
    }
  }
  out[(size_t)y * 1024 + x] = acc;
}

// ---------------------------------------------------------------------------
// Launch. Workspace (adaptive to ws_size):
//   Hs: 8 MiB  — shuffled h, both images, persists
//   A : max(32ch*(S+6)*1024*4, 16.8 MB)  — z1/z3 strip buf; encoder ping (2 img)
//   B : max(64ch*(S+4)*1024*4, 33.6 MB)  — z2/z4 strip buf; encoder pong (2 img)
// S = largest of {1024,512,256,128,64} fitting ws_size.
// Encoder/decoder batches BOTH images per dispatch (fills 256 CUs at 256²).
// z-branch runs per image in row strips of height S with halo-recompute
// (identical numerics to full-image conv).
// ---------------------------------------------------------------------------
extern "C" void kernel_launch(void* const* d_in, const int* in_sizes, int n_in,
                              void* d_out, int out_size, void* d_ws, size_t ws_size,
                              hipStream_t stream) {
  const float* x    = (const float*)d_in[0];
  const float* w_e1 = (const float*)d_in[1];
  const float* w_e2 = (const float*)d_in[2];
  const float* w_e3 = (const float*)d_in[3];
  const float* w_d1 = (const float*)d_in[4];
  const float* w_d2 = (const float*)d_in[5];
  const float* w_k1 = (const float*)d_in[6];
  const float* w_k2 = (const float*)d_in[7];
  const float* w_k3 = (const float*)d_in[8];
  const float* w_k4 = (const float*)d_in[9];

  const size_t HS_SZ = 8388608;                 // 2 * 1024*1024 * 4
  const size_t AMIN  = 16777216;                // 2 img * 32ch @256²
  const size_t BMIN  = 33554432;                // 2 img * 64ch @256²

  int S = 64;
  {
    const int cand[5] = {1024, 512, 256, 128, 64};
    for (int i = 0; i < 5; ++i) {
      int s = cand[i];
      size_t a = 32ull * (size_t)(s + 6) * 1024 * 4; if (a < AMIN) a = AMIN;
      size_t b = 64ull * (size_t)(s + 4) * 1024 * 4; if (b < BMIN) b = BMIN;
      if (HS_SZ + a + b <= ws_size) { S = s; break; }
    }
  }
  size_t A_SZ = 32ull * (size_t)(S + 6) * 1024 * 4; if (A_SZ < AMIN) A_SZ = AMIN;

  char* ws = (char*)d_ws;
  float* Hs = (float*)(ws);
  float* A  = (float*)(ws + HS_SZ);
  float* B  = (float*)(ws + HS_SZ + A_SZ);
  float* outp = (float*)d_out;

  dim3 blk(256);

  // ---- encoder/decoder @256², both images per dispatch, ping-pong A<->B ----
  // grid: (256/32, 256/16, 2*NCB)
  conv3x3_relu_k<1, 16, 16, 2><<<dim3(8, 16, 2), blk, 0, stream>>>(x, w_e1, B, 256, 0, 256, 0, 256);
  conv3x3_relu_k<16, 32, 32, 2><<<dim3(8, 16, 2), blk, 0, stream>>>(B, w_e2, A, 256, 0, 256, 0, 256);
  conv3x3_relu_k<32, 64, 32, 2><<<dim3(8, 16, 4), blk, 0, stream>>>(A, w_e3, B, 256, 0, 256, 0, 256);
  conv3x3_relu_k<64, 32, 32, 2><<<dim3(8, 16, 2), blk, 0, stream>>>(B, w_d1, A, 256, 0, 256, 0, 256);
  conv3x3_relu_k<32, 16, 16, 2><<<dim3(8, 16, 2), blk, 0, stream>>>(A, w_d2, B, 256, 0, 256, 0, 256);
  pixel_shuffle_relu_k<<<dim3(8192), blk, 0, stream>>>(B, Hs);

  // ---- kernel-prediction branch + dynamic conv, per image, row strips ----
  const int nstr = 1024 / S;
  for (int n = 0; n < 2; ++n) {
    const float* himg = Hs + (size_t)n * 1048576;
    float* outn = outp + (size_t)n * 1048576;
    for (int s = 0; s < nstr; ++s) {
      const int r0 = s * S, r1 = r0 + S;
      const int z1y0 = (r0 - 3 > 0) ? r0 - 3 : 0;
      const int z1r  = ((r1 + 3 < 1024) ? r1 + 3 : 1024) - z1y0;
      const int z2y0 = (r0 - 2 > 0) ? r0 - 2 : 0;
      const int z2r  = ((r1 + 2 < 1024) ? r1 + 2 : 1024) - z2y0;
      const int z3y0 = (r0 - 1 > 0) ? r0 - 1 : 0;
      const int z3r  = ((r1 + 1 < 1024) ? r1 + 1 : 1024) - z3y0;
      const int g1 = (z1r + 15) / 16, g2 = (z2r + 15) / 16, g3 = (z3r + 15) / 16;

      conv3x3_relu_k<1, 32, 32, 2><<<dim3(32, g1, 1), blk, 0, stream>>>(
          himg, w_k1, A, 1024, 0, 1024, z1y0, z1r);
      conv3x3_relu_k<32, 64, 32, 2><<<dim3(32, g2, 2), blk, 0, stream>>>(
          A, w_k2, B, 1024, z1y0, z1r, z2y0, z2r);
      conv3x3_relu_k<64, 32, 32, 2><<<dim3(32, g3, 1), blk, 0, stream>>>(
          B, w_k3, A, 1024, z2y0, z2r, z3y0, z3r);
      conv3x3_relu_k<32, 25, 25, 2><<<dim3(32, S / 16, 1), blk, 0, stream>>>(
          A, w_k4, B, 1024, z3y0, z3r, r0, S);
      pixel_conv_add_k<<<dim3(64, S / 16), blk, 0, stream>>>(
          himg, B, outn, r0, S);
    }
  }
}

// Round 2
// 3312.425 us; speedup vs baseline: 1.7954x; 1.6729x over previous
//
#include <hip/hip_runtime.h>

// ---------------------------------------------------------------------------
// Direct 3x3 SAME conv + ReLU, fp32, row-range aware, v3: NO LDS, NO BARRIERS.
//
// Block: 256 threads = 64-wide x 8-tall output tile (4 y-groups x P=2 rows).
// Thread (lx, yg) owns P=2 output rows at column x. CB output channels
// accumulate in VGPRs (acc[CB][P]).
//
// Per input channel ci:
//   - 12 global_load_dword: taps (P+2 rows x 3 cols) at SGPR channel base +
//     per-thread 32-bit voffset (offsets computed ONCE, constant across ci;
//     only the scalar base steps per channel). Working set per block per ci
//     is ~2.5 KB -> L1-resident; lane/halo redundancy served by L1/L2.
//   - CB*P*9 = 576 fmac with wave-uniform weights (s_load -> SGPR operand),
//     p-chains interleaved for dependency hiding.
//   - no __syncthreads anywhere: waves free-run, TLP hides load latency.
//
// Boundary handling: row offsets clamped to [0, in_rows-1], col offsets
// clamped to the channel's byte range -> every address in-bounds within the
// current channel. Blocks touching any image/buffer edge (block-uniform
// test) multiply taps by 0/1 masks; interior blocks skip it.
//
// Input buffer holds rows [in_y0, in_y0+in_rows); output receives rows
// [out_y0, out_y0+out_rows). Sampling outside buffer rows / [0,W) cols
// yields zero == SAME padding (strip buffers always contain every in-image
// row a consumer needs).
// ---------------------------------------------------------------------------
template<int CIN, int COUT, int CB, int P, int W>
__global__ __launch_bounds__(256, 4) void conv3x3_relu_k(
    const float* __restrict__ in, const float* __restrict__ wt,
    float* __restrict__ out,
    int in_y0, int in_rows, int out_y0, int out_rows)
{
  static_assert(COUT % CB == 0, "CB must divide COUT");
  constexpr int NCB = COUT / CB;
  constexpr int TW  = 64;
  constexpr int TH  = 4 * P;                  // 8 rows per block

  const int n   = blockIdx.z / NCB;           // image index
  const int co0 = (blockIdx.z % NCB) * CB;
  const int lx  = threadIdx.x & 63;
  const int yg  = threadIdx.x >> 6;
  const int x0  = blockIdx.x * TW;
  const int x   = x0 + lx;
  const int oy0 = out_y0 + blockIdx.y * TH;   // image row of tile top
  const int yb  = yg * P;

  const int maxoff = in_rows * W * 4 - 4;     // last valid byte offset in chan

  // ---- per-thread tap offsets + masks (constant across ci) ----
  int   voff[P + 2][3];
  float mrow[P + 2];
#pragma unroll
  for (int r = 0; r < P + 2; ++r) {
    int ry = oy0 + yb + r - 1 - in_y0;        // buffer-relative row
    mrow[r] = (ry >= 0 && ry < in_rows) ? 1.f : 0.f;
    int ryc = ry < 0 ? 0 : (ry >= in_rows ? in_rows - 1 : ry);
    int vo  = (ryc * W + x) * 4;
    voff[r][1] = vo;
    voff[r][0] = (vo > 4 ? vo : 4) - 4;       // clamped left tap, never < 0
    int vr = vo + 4;
    voff[r][2] = vr < maxoff ? vr : maxoff;   // clamped right tap, in-bounds
  }
  const float ml = (x == 0)     ? 0.f : 1.f;
  const float mr = (x == W - 1) ? 0.f : 1.f;

  const bool interior =
      (x0 > 0) && (x0 + TW < W) &&
      ((oy0 - 1 - in_y0) >= 0) && ((oy0 + TH - in_y0) < in_rows);

  float acc[CB][P];
#pragma unroll
  for (int j = 0; j < CB; ++j)
#pragma unroll
    for (int p = 0; p < P; ++p) acc[j][p] = 0.f;

  const float* inN = in + (size_t)n * CIN * in_rows * W;   // uniform -> SGPR
  const size_t chbytes = (size_t)in_rows * W * 4;

#pragma unroll 1
  for (int ci = 0; ci < CIN; ++ci) {
    const char* bp = (const char*)inN + (size_t)ci * chbytes;  // scalar step

    float va[P + 2][3];
#pragma unroll
    for (int r = 0; r < P + 2; ++r)
#pragma unroll
      for (int c = 0; c < 3; ++c)
        va[r][c] = *(const float*)(bp + voff[r][c]);

    if (!interior) {                          // block-uniform branch
#pragma unroll
      for (int r = 0; r < P + 2; ++r) {
#pragma unroll
        for (int c = 0; c < 3; ++c) {
          float m = mrow[r];
          if (c == 0) m *= ml;
          if (c == 2) m *= mr;
          va[r][c] *= m;
        }
      }
    }

#pragma unroll
    for (int j = 0; j < CB; ++j) {
      const float* wp = wt + ((size_t)(co0 + j) * CIN + ci) * 9;  // uniform
      float w[9];
#pragma unroll
      for (int t = 0; t < 9; ++t) w[t] = wp[t];
#pragma unroll
      for (int t = 0; t < 9; ++t) {
        const int r = t / 3, c = t - r * 3;
#pragma unroll
        for (int p = 0; p < P; ++p)           // p-interleave: 2 indep chains
          acc[j][p] = fmaf(va[p + r][c], w[t], acc[j][p]);
      }
    }
  }

  // ---- epilogue: ReLU + store ----
  float* outN = out + (size_t)n * COUT * out_rows * W;
#pragma unroll
  for (int p = 0; p < P; ++p) {
    const int orow = (oy0 + yb + p) - out_y0;
    if (orow < out_rows) {
#pragma unroll
      for (int j = 0; j < CB; ++j) {
        float v = acc[j][p] < 0.f ? 0.f : acc[j][p];
        outN[((size_t)(co0 + j) * out_rows + orow) * W + x] = v;
      }
    }
  }
}

// ---------------------------------------------------------------------------
// PixelShuffle r=4 + ReLU, BOTH images: (2,16,256,256) -> (2,1024,1024)
// out[n, 4*hh+ii, 4*ww+jj] = in[n, ii*4+jj, hh, ww]
// ---------------------------------------------------------------------------
__global__ __launch_bounds__(256) void pixel_shuffle_relu_k(
    const float* __restrict__ in, float* __restrict__ out)
{
  int i = blockIdx.x * 256 + threadIdx.x;      // over 2*1024*1024
  int n = i >> 20;
  int p = i & 1048575;
  int x = p & 1023, y = p >> 10;
  int c = (y & 3) * 4 + (x & 3);
  float v = in[((size_t)(n * 16 + c) * 256 + (y >> 2)) * 256 + (x >> 2)];
  out[i] = v < 0.f ? 0.f : v;
}

// ---------------------------------------------------------------------------
// Per-pixel 5x5 dynamic conv + residual, one image, one row-strip:
// out[y,x] = h[y,x] + sum_{kw,kh} h_pad[y+kh-2, x+kw-2] * ker[kw*5+kh, y, x]
// ker holds rows [ky0, ky0+krows) of the image (channel stride krows*1024).
// ---------------------------------------------------------------------------
__global__ __launch_bounds__(256) void pixel_conv_add_k(
    const float* __restrict__ h,    // full image (1024,1024)
    const float* __restrict__ ker,  // (25, krows, 1024)
    float* __restrict__ out,        // full image (1024,1024)
    int ky0, int krows)
{
  const int tx = threadIdx.x & 15, ty = threadIdx.x >> 4;
  const int x0 = blockIdx.x * 16;
  const int y0 = ky0 + blockIdx.y * 16;

  __shared__ float tile[20][21];
  for (int t = threadIdx.x; t < 20 * 20; t += 256) {
    int r = t / 20, c = t - r * 20;
    int yy = y0 + r - 2, xx = x0 + c - 2;
    float v = 0.f;
    if (yy >= 0 && yy < 1024 && xx >= 0 && xx < 1024) v = h[(size_t)yy * 1024 + xx];
    tile[r][c] = v;
  }
  __syncthreads();

  const int x = x0 + tx, y = y0 + ty;
  float acc = tile[ty + 2][tx + 2];            // residual h
  const size_t kpix = (size_t)(y - ky0) * 1024 + x;
#pragma unroll
  for (int kw = 0; kw < 5; ++kw) {
#pragma unroll
    for (int kh = 0; kh < 5; ++kh) {
      float kv = ker[(size_t)(kw * 5 + kh) * krows * 1024 + kpix];
      acc = fmaf(tile[ty + kh][tx + kw], kv, acc);
    }
  }
  out[(size_t)y * 1024 + x] = acc;
}

// ---------------------------------------------------------------------------
// Launch. Workspace (adaptive to ws_size):
//   Hs: 8 MiB  — shuffled h, both images, persists
//   A : max(32ch*(S+6)*1024*4, 16.8 MB)  — z1/z3 strip buf; encoder ping (2 img)
//   B : max(64ch*(S+4)*1024*4, 33.6 MB)  — z2/z4 strip buf; encoder pong (2 img)
// S = largest of {1024,512,256,128,64} fitting ws_size.
// Encoder/decoder batches BOTH images per dispatch.
// z-branch runs per image in row strips of height S with halo-recompute
// (identical numerics to full-image conv).
// ---------------------------------------------------------------------------
extern "C" void kernel_launch(void* const* d_in, const int* in_sizes, int n_in,
                              void* d_out, int out_size, void* d_ws, size_t ws_size,
                              hipStream_t stream) {
  const float* x    = (const float*)d_in[0];
  const float* w_e1 = (const float*)d_in[1];
  const float* w_e2 = (const float*)d_in[2];
  const float* w_e3 = (const float*)d_in[3];
  const float* w_d1 = (const float*)d_in[4];
  const float* w_d2 = (const float*)d_in[5];
  const float* w_k1 = (const float*)d_in[6];
  const float* w_k2 = (const float*)d_in[7];
  const float* w_k3 = (const float*)d_in[8];
  const float* w_k4 = (const float*)d_in[9];

  const size_t HS_SZ = 8388608;                 // 2 * 1024*1024 * 4
  const size_t AMIN  = 16777216;                // 2 img * 32ch @256²
  const size_t BMIN  = 33554432;                // 2 img * 64ch @256²

  int S = 64;
  {
    const int cand[5] = {1024, 512, 256, 128, 64};
    for (int i = 0; i < 5; ++i) {
      int s = cand[i];
      size_t a = 32ull * (size_t)(s + 6) * 1024 * 4; if (a < AMIN) a = AMIN;
      size_t b = 64ull * (size_t)(s + 4) * 1024 * 4; if (b < BMIN) b = BMIN;
      if (HS_SZ + a + b <= ws_size) { S = s; break; }
    }
  }
  size_t A_SZ = 32ull * (size_t)(S + 6) * 1024 * 4; if (A_SZ < AMIN) A_SZ = AMIN;

  char* ws = (char*)d_ws;
  float* Hs = (float*)(ws);
  float* A  = (float*)(ws + HS_SZ);
  float* B  = (float*)(ws + HS_SZ + A_SZ);
  float* outp = (float*)d_out;

  dim3 blk(256);

  // ---- encoder/decoder @256², both images per dispatch, ping-pong A<->B ----
  // grid: (256/64, 256/8, 2*NCB)
  conv3x3_relu_k<1, 16, 16, 2, 256><<<dim3(4, 32, 2), blk, 0, stream>>>(x, w_e1, B, 0, 256, 0, 256);
  conv3x3_relu_k<16, 32, 32, 2, 256><<<dim3(4, 32, 2), blk, 0, stream>>>(B, w_e2, A, 0, 256, 0, 256);
  conv3x3_relu_k<32, 64, 32, 2, 256><<<dim3(4, 32, 4), blk, 0, stream>>>(A, w_e3, B, 0, 256, 0, 256);
  conv3x3_relu_k<64, 32, 32, 2, 256><<<dim3(4, 32, 2), blk, 0, stream>>>(B, w_d1, A, 0, 256, 0, 256);
  conv3x3_relu_k<32, 16, 16, 2, 256><<<dim3(4, 32, 2), blk, 0, stream>>>(A, w_d2, B, 0, 256, 0, 256);
  pixel_shuffle_relu_k<<<dim3(8192), blk, 0, stream>>>(B, Hs);

  // ---- kernel-prediction branch + dynamic conv, per image, row strips ----
  const int nstr = 1024 / S;
  for (int n = 0; n < 2; ++n) {
    const float* himg = Hs + (size_t)n * 1048576;
    float* outn = outp + (size_t)n * 1048576;
    for (int s = 0; s < nstr; ++s) {
      const int r0 = s * S, r1 = r0 + S;
      const int z1y0 = (r0 - 3 > 0) ? r0 - 3 : 0;
      const int z1r  = ((r1 + 3 < 1024) ? r1 + 3 : 1024) - z1y0;
      const int z2y0 = (r0 - 2 > 0) ? r0 - 2 : 0;
      const int z2r  = ((r1 + 2 < 1024) ? r1 + 2 : 1024) - z2y0;
      const int z3y0 = (r0 - 1 > 0) ? r0 - 1 : 0;
      const int z3r  = ((r1 + 1 < 1024) ? r1 + 1 : 1024) - z3y0;
      const int g1 = (z1r + 7) / 8, g2 = (z2r + 7) / 8, g3 = (z3r + 7) / 8;

      conv3x3_relu_k<1, 32, 32, 2, 1024><<<dim3(16, g1, 1), blk, 0, stream>>>(
          himg, w_k1, A, 0, 1024, z1y0, z1r);
      conv3x3_relu_k<32, 64, 32, 2, 1024><<<dim3(16, g2, 2), blk, 0, stream>>>(
          A, w_k2, B, z1y0, z1r, z2y0, z2r);
      conv3x3_relu_k<64, 32, 32, 2, 1024><<<dim3(16, g3, 1), blk, 0, stream>>>(
          B, w_k3, A, z2y0, z2r, z3y0, z3r);
      conv3x3_relu_k<32, 25, 25, 2, 1024><<<dim3(16, S / 8, 1), blk, 0, stream>>>(
          A, w_k4, B, z3y0, z3r, r0, S);
      pixel_conv_add_k<<<dim3(64, S / 16), blk, 0, stream>>>(
          himg, B, outn, r0, S);
    }
  }
}